// Round 13
// baseline (275.167 us; speedup 1.0000x reference)
//
#include <hip/hip_runtime.h>

#define NN 19        // nodes
#define NT 4096
#define LAT 512
#define HID 2048
#define NE 342       // edges

// ---------------------------------------------------------------------------
// Build M = I + adjacency-count (19x19) into sM from edge_idx. cnt[] aliases
// scratch LDS. Edge buffer may be int64 (pairs of int32) or int32, detected
// via odd-word check (values in [0,19) => int64 high words all zero).
// ---------------------------------------------------------------------------
__device__ __forceinline__ void build_M(const int* __restrict__ ei, float* sM,
                                        int* scratch, int t, int bs) {
    int* cnt = scratch;
    int* flag = scratch + NN * NN;
    if (t == 0) *flag = 0;
    for (int i = t; i < NN * NN; i += bs) cnt[i] = 0;
    __syncthreads();
    int f = 0;
    for (int i = t; i < NE; i += bs) f |= ei[2 * i + 1];
    if (f) atomicOr(flag, 1);
    __syncthreads();
    const bool i64 = (*flag == 0);
    for (int i = t; i < NE; i += bs) {
        const int s = i64 ? ei[2 * i] : ei[i];
        const int d = i64 ? ei[2 * NE + 2 * i] : ei[NE + i];
        atomicAdd(&cnt[d * NN + s], 1);
    }
    __syncthreads();
    for (int i = t; i < NN * NN; i += bs)
        sM[i] = (float)cnt[i] + ((i / NN) == (i % NN) ? 1.f : 0.f);
    __syncthreads();
}

// ---------------------------------------------------------------------------
// GEMM inner: acc[19][4 cols] over a BK k-slice staged in sA[k*21+i].
// ---------------------------------------------------------------------------
template <int BK, int N>
__device__ __forceinline__ void gemm_inner(int col, int kc,
                                           const float* __restrict__ W,
                                           float* __restrict__ part,
                                           const float* __restrict__ sA) {
    const int k0 = kc * BK;
    const float4* __restrict__ w = (const float4*)(W + (size_t)k0 * N + col);
    float4 acc[NN];
#pragma unroll
    for (int i = 0; i < NN; ++i) acc[i] = make_float4(0.f, 0.f, 0.f, 0.f);
#pragma unroll 1
    for (int kk = 0; kk < BK; kk += 8) {
        float4 wb[8];
#pragma unroll
        for (int u = 0; u < 8; ++u) wb[u] = w[(size_t)(kk + u) * (N / 4)];
#pragma unroll
        for (int u = 0; u < 8; ++u) {
#pragma unroll
            for (int i = 0; i < NN; ++i) {
                const float av = sA[(kk + u) * 21 + i];
                acc[i].x = fmaf(av, wb[u].x, acc[i].x);
                acc[i].y = fmaf(av, wb[u].y, acc[i].y);
                acc[i].z = fmaf(av, wb[u].z, acc[i].z);
                acc[i].w = fmaf(av, wb[u].w, acc[i].w);
            }
        }
    }
    float* __restrict__ p = part + (size_t)kc * NN * N + col;
#pragma unroll
    for (int i = 0; i < NN; ++i) *(float4*)(p + (size_t)i * N) = acc[i];
}

// K1: part1 = (M @ z) @ W1a.  K=512, BK=32; grid (cb=2, kc=16). Zeroes ticket.
__global__ __launch_bounds__(256) void gemm_l1a(const float* __restrict__ z,
                                                const int* __restrict__ ei,
                                                const float* __restrict__ W1a,
                                                float* __restrict__ part1,
                                                unsigned int* __restrict__ counter) {
    __shared__ __align__(16) float sA[32 * 21];
    __shared__ __align__(16) float sZ[32 * 21];
    __shared__ float sM[NN * NN];
    __shared__ int scratch[NN * NN + 1];
    const int t = threadIdx.x, cb = blockIdx.x, kc = blockIdx.y;
    const int k0 = kc * 32;
    if (cb == 0 && kc == 0 && t == 0) *counter = 0u;
    build_M(ei, sM, scratch, t, 256);
    for (int idx = t; idx < NN * 32; idx += 256) {
        const int s = idx / 32, c = idx % 32;
        sZ[c * 21 + s] = z[(size_t)s * LAT + k0 + c];
    }
    __syncthreads();
    for (int idx = t; idx < NN * 32; idx += 256) {
        const int i = idx / 32, c = idx % 32;
        float acc = 0.f;
#pragma unroll
        for (int s = 0; s < NN; ++s) acc = fmaf(sM[i * NN + s], sZ[c * 21 + s], acc);
        sA[c * 21 + i] = acc;
    }
    __syncthreads();
    gemm_inner<32, HID>(cb * 1024 + 4 * t, kc, W1a, part1, sA);
}

// K2: part2 = relu(reduce16(part1)+b1a) @ W1b.  K=2048, BK=64; grid (2, 32)
__global__ __launch_bounds__(256) void gemm_l1b(const float* __restrict__ part1,
                                                const float* __restrict__ b1a,
                                                const float* __restrict__ W1b,
                                                float* __restrict__ part2) {
    __shared__ __align__(16) float sA[64 * 21];
    const int t = threadIdx.x, cb = blockIdx.x, kc = blockIdx.y;
    const int k0 = kc * 64;
    for (int idx = t; idx < NN * 64; idx += 256) {
        const int i = idx / 64, c = idx % 64;
        const int k = k0 + c;
        float s = b1a[k];
#pragma unroll
        for (int cc = 0; cc < 16; ++cc) s += part1[((size_t)cc * NN + i) * HID + k];
        sA[c * 21 + i] = s > 0.f ? s : 0.f;
    }
    __syncthreads();
    gemm_inner<64, HID>(cb * 1024 + 4 * t, kc, W1b, part2, sA);
}

// K3: part3 = (M @ relu(reduce32(part2)+b1b)) @ W2a.  K=2048, BK=64; grid (4,32)
__global__ __launch_bounds__(256) void gemm_l2a(const float* __restrict__ part2,
                                                const float* __restrict__ b1b,
                                                const int* __restrict__ ei,
                                                const float* __restrict__ W2a,
                                                float* __restrict__ part3) {
    __shared__ __align__(16) float sA[64 * 21];
    __shared__ __align__(16) float sZ[64 * 21];
    __shared__ float sM[NN * NN];
    __shared__ int scratch[NN * NN + 1];
    const int t = threadIdx.x, cb = blockIdx.x, kc = blockIdx.y;
    const int k0 = kc * 64;
    build_M(ei, sM, scratch, t, 256);
    for (int idx = t; idx < NN * 64; idx += 256) {
        const int i = idx / 64, c = idx % 64;
        const int k = k0 + c;
        float s = b1b[k];
#pragma unroll
        for (int cc = 0; cc < 32; ++cc) s += part2[((size_t)cc * NN + i) * HID + k];
        sZ[c * 21 + i] = s > 0.f ? s : 0.f;
    }
    __syncthreads();
    for (int idx = t; idx < NN * 64; idx += 256) {
        const int i = idx / 64, c = idx % 64;
        float acc = 0.f;
#pragma unroll
        for (int s = 0; s < NN; ++s) acc = fmaf(sM[i * NN + s], sZ[c * 21 + s], acc);
        sA[c * 21 + i] = acc;
    }
    __syncthreads();
    gemm_inner<64, NT>(cb * 1024 + 4 * t, kc, W2a, part3, sA);
}

// K4: part4 = relu(reduce32(part3)+b2a) @ W2b.  K=4096, BK=64; grid (4, 64)
__global__ __launch_bounds__(256) void gemm_l2b(const float* __restrict__ part3,
                                                const float* __restrict__ b2a,
                                                const float* __restrict__ W2b,
                                                float* __restrict__ part4) {
    __shared__ __align__(16) float sA[64 * 21];
    const int t = threadIdx.x, cb = blockIdx.x, kc = blockIdx.y;
    const int k0 = kc * 64;
    for (int idx = t; idx < NN * 64; idx += 256) {
        const int i = idx / 64, c = idx % 64;
        const int k = k0 + c;
        float s = b2a[k];
#pragma unroll
        for (int cc = 0; cc < 32; ++cc) s += part3[((size_t)cc * NN + i) * NT + k];
        sA[c * 21 + i] = s > 0.f ? s : 0.f;
    }
    __syncthreads();
    gemm_inner<64, NT>(cb * 1024 + 4 * t, kc, W2b, part4, sA);
}

// K5: flat = reduce64(part4)+b2b -> out+1.  76 blocks x 256 threads, float4.
__global__ __launch_bounds__(256) void reduce_out(const float* __restrict__ part4,
                                                  const float* __restrict__ b2b,
                                                  float* __restrict__ out1) {
    const int f = blockIdx.x * 256 + threadIdx.x;
    const int i = f / (NT / 4), n4 = f % (NT / 4);
    const float4 b = ((const float4*)b2b)[n4];
    float4 s = b;
    const float4* __restrict__ p = (const float4*)part4 + (size_t)i * (NT / 4) + n4;
#pragma unroll 16
    for (int c = 0; c < 64; ++c) {
        const float4 v = p[(size_t)c * NN * (NT / 4)];
        s.x += v.x; s.y += v.y; s.z += v.z; s.w += v.w;
    }
    float* __restrict__ o = out1 + ((size_t)i * (NT / 4) + n4) * 4;
    o[0] = s.x; o[1] = s.y; o[2] = s.z; o[3] = s.w;
}

// ---------------------------------------------------------------------------
// K6 (occupancy classifier): 2048 blocks x 256 threads, 38 rows per block
// (77824 = 2048*38). Full CU occupancy (8 blocks/CU, 32 waves/CU) so that
// even 1-outstanding-load-per-wave aggregates to ~4.7 TB/s device-wide.
// Thread t owns cols (2t, 2t+1); flat[k] wave-uniform; per-block partial
// dotted with Wc2 -> scal[b]; device-scope ticket: last of 2048 blocks sums
// scalars + bc1.Wc2 + bc2 -> sigmoid -> out[0].
// ---------------------------------------------------------------------------
__global__ __launch_bounds__(256) void cls_gs(const float* __restrict__ flat,
                                              const float* __restrict__ Wc1,
                                              const float* __restrict__ bc1,
                                              const float* __restrict__ Wc2,
                                              const float* __restrict__ bc2,
                                              float* __restrict__ out,
                                              float* __restrict__ scal,
                                              unsigned int* __restrict__ counter) {
    __shared__ float red[256];
    __shared__ int lastFlag;
    const int t = threadIdx.x;
    const int b = blockIdx.x;          // 0..2047
    const int rbase = b * 38;
    const float2* __restrict__ wp = (const float2*)Wc1 + (size_t)rbase * 256 + t;

    float accx = 0.f, accy = 0.f;
#pragma unroll 2
    for (int s = 0; s < 38; ++s) {
        const float2 wv = wp[(size_t)s * 256];
        const float f = flat[rbase + s];
        accx = fmaf(f, wv.x, accx);
        accy = fmaf(f, wv.y, accy);
    }

    // block scalar = partial . Wc2
    const float2 wv2 = ((const float2*)Wc2)[t];
    red[t] = accx * wv2.x + accy * wv2.y;
    __syncthreads();
    for (int off = 128; off > 0; off >>= 1) {
        if (t < off) red[t] += red[t + off];
        __syncthreads();
    }
    if (t == 0) scal[b] = red[0];
    __threadfence();  // release scal device-wide (cross-XCD)
    __syncthreads();
    if (t == 0) lastFlag = (atomicAdd(counter, 1u) == 2047u) ? 1 : 0;
    __syncthreads();
    if (!lastFlag) return;
    __threadfence();  // acquire before reading all scal

    float s = 0.f;
#pragma unroll
    for (int c = 0; c < 8; ++c) s += scal[t + 256 * c];
    const float2 b1 = ((const float2*)bc1)[t];
    s += b1.x * wv2.x + b1.y * wv2.y;
    red[t] = s;
    __syncthreads();
    for (int off = 128; off > 0; off >>= 1) {
        if (t < off) red[t] += red[t + off];
        __syncthreads();
    }
    if (t == 0) out[0] = 1.f / (1.f + expf(-(red[0] + bc2[0])));
}

extern "C" void kernel_launch(void* const* d_in, const int* in_sizes, int n_in,
                              void* d_out, int out_size, void* d_ws, size_t ws_size,
                              hipStream_t stream) {
    const float* z   = (const float*)d_in[0];
    const int*   ei  = (const int*)d_in[1];
    const float* W1a = (const float*)d_in[2];
    const float* b1a = (const float*)d_in[3];
    const float* W1b = (const float*)d_in[4];
    const float* b1b = (const float*)d_in[5];
    const float* W2a = (const float*)d_in[6];
    const float* b2a = (const float*)d_in[7];
    const float* W2b = (const float*)d_in[8];
    const float* b2b = (const float*)d_in[9];
    const float* Wc1 = (const float*)d_in[10];
    const float* bc1 = (const float*)d_in[11];
    const float* Wc2 = (const float*)d_in[12];
    const float* bc2 = (const float*)d_in[13];
    float* out = (float*)d_out;
    float* ws  = (float*)d_ws;

    // workspace layout (float offsets)
    unsigned int* counter = (unsigned int*)ws;  // ticket, reset by K1 each call
    float* part1 = ws + 262144;    // 16*19*2048 =   622,592
    float* part2 = ws + 1048576;   // 32*19*2048 = 1,245,184
    float* part3 = ws + 2359296;   // 32*19*4096 = 2,490,368
    float* part4 = ws + 4980736;   // 64*19*4096 = 4,980,736
    float* scal  = ws + 10485760;  // 2048

    gemm_l1a<<<dim3(2, 16), 256, 0, stream>>>(z, ei, W1a, part1, counter);
    gemm_l1b<<<dim3(2, 32), 256, 0, stream>>>(part1, b1a, W1b, part2);
    gemm_l2a<<<dim3(4, 32), 256, 0, stream>>>(part2, b1b, ei, W2a, part3);
    gemm_l2b<<<dim3(4, 64), 256, 0, stream>>>(part3, b2a, W2b, part4);
    reduce_out<<<76, 256, 0, stream>>>(part4, b2b, out + 1);
    cls_gs<<<2048, 256, 0, stream>>>(out + 1, Wc1, bc1, Wc2, bc2,
                                     out, scal, counter);
}

// Round 14
// 224.100 us; speedup vs baseline: 1.2279x; 1.2279x over previous
//
#include <hip/hip_runtime.h>

#define NN 19        // nodes
#define NT 4096
#define LAT 512
#define HID 2048
#define NE 342       // edges

// ---------------------------------------------------------------------------
// Async global->LDS DMA, 16 B per lane (global_load_lds_dwordx4).
// gsrc is PER-LANE (base + lane*16B); ldst WAVE-UNIFORM; HW writes lane i's
// 16 B at ldst + i*16.  (r9-verified.)
// ---------------------------------------------------------------------------
__device__ __forceinline__ void stage16B(const void* gsrc, void* ldst) {
    __builtin_amdgcn_global_load_lds(
        reinterpret_cast<const __attribute__((address_space(1))) void*>(
            reinterpret_cast<uintptr_t>(gsrc)),
        reinterpret_cast<__attribute__((address_space(3))) void*>(
            reinterpret_cast<uintptr_t>(ldst)),
        16, 0, 0);
}

// ---------------------------------------------------------------------------
// Build M = I + adjacency-count (19x19) into sM from edge_idx. cnt[] aliases
// scratch LDS. Edge buffer may be int64 (pairs of int32) or int32, detected
// via odd-word check (values in [0,19) => int64 high words all zero).
// ---------------------------------------------------------------------------
__device__ __forceinline__ void build_M(const int* __restrict__ ei, float* sM,
                                        int* scratch, int t, int bs) {
    int* cnt = scratch;
    int* flag = scratch + NN * NN;
    if (t == 0) *flag = 0;
    for (int i = t; i < NN * NN; i += bs) cnt[i] = 0;
    __syncthreads();
    int f = 0;
    for (int i = t; i < NE; i += bs) f |= ei[2 * i + 1];
    if (f) atomicOr(flag, 1);
    __syncthreads();
    const bool i64 = (*flag == 0);
    for (int i = t; i < NE; i += bs) {
        const int s = i64 ? ei[2 * i] : ei[i];
        const int d = i64 ? ei[2 * NE + 2 * i] : ei[NE + i];
        atomicAdd(&cnt[d * NN + s], 1);
    }
    __syncthreads();
    for (int i = t; i < NN * NN; i += bs)
        sM[i] = (float)cnt[i] + ((i / NN) == (i % NN) ? 1.f : 0.f);
    __syncthreads();
}

// ---------------------------------------------------------------------------
// GEMM inner: acc[19][4 cols] over a BK k-slice staged in sA[k*21+i].
// ---------------------------------------------------------------------------
template <int BK, int N>
__device__ __forceinline__ void gemm_inner(int col, int kc,
                                           const float* __restrict__ W,
                                           float* __restrict__ part,
                                           const float* __restrict__ sA) {
    const int k0 = kc * BK;
    const float4* __restrict__ w = (const float4*)(W + (size_t)k0 * N + col);
    float4 acc[NN];
#pragma unroll
    for (int i = 0; i < NN; ++i) acc[i] = make_float4(0.f, 0.f, 0.f, 0.f);
#pragma unroll 1
    for (int kk = 0; kk < BK; kk += 8) {
        float4 wb[8];
#pragma unroll
        for (int u = 0; u < 8; ++u) wb[u] = w[(size_t)(kk + u) * (N / 4)];
#pragma unroll
        for (int u = 0; u < 8; ++u) {
#pragma unroll
            for (int i = 0; i < NN; ++i) {
                const float av = sA[(kk + u) * 21 + i];
                acc[i].x = fmaf(av, wb[u].x, acc[i].x);
                acc[i].y = fmaf(av, wb[u].y, acc[i].y);
                acc[i].z = fmaf(av, wb[u].z, acc[i].z);
                acc[i].w = fmaf(av, wb[u].w, acc[i].w);
            }
        }
    }
    float* __restrict__ p = part + (size_t)kc * NN * N + col;
#pragma unroll
    for (int i = 0; i < NN; ++i) *(float4*)(p + (size_t)i * N) = acc[i];
}

// K1: part1 = (M @ z) @ W1a.  K=512, BK=32; grid (cb=2, kc=16). Zeroes ticket.
__global__ __launch_bounds__(256) void gemm_l1a(const float* __restrict__ z,
                                                const int* __restrict__ ei,
                                                const float* __restrict__ W1a,
                                                float* __restrict__ part1,
                                                unsigned int* __restrict__ counter) {
    __shared__ __align__(16) float sA[32 * 21];
    __shared__ __align__(16) float sZ[32 * 21];
    __shared__ float sM[NN * NN];
    __shared__ int scratch[NN * NN + 1];
    const int t = threadIdx.x, cb = blockIdx.x, kc = blockIdx.y;
    const int k0 = kc * 32;
    if (cb == 0 && kc == 0 && t == 0) *counter = 0u;
    build_M(ei, sM, scratch, t, 256);
    for (int idx = t; idx < NN * 32; idx += 256) {
        const int s = idx / 32, c = idx % 32;
        sZ[c * 21 + s] = z[(size_t)s * LAT + k0 + c];
    }
    __syncthreads();
    for (int idx = t; idx < NN * 32; idx += 256) {
        const int i = idx / 32, c = idx % 32;
        float acc = 0.f;
#pragma unroll
        for (int s = 0; s < NN; ++s) acc = fmaf(sM[i * NN + s], sZ[c * 21 + s], acc);
        sA[c * 21 + i] = acc;
    }
    __syncthreads();
    gemm_inner<32, HID>(cb * 1024 + 4 * t, kc, W1a, part1, sA);
}

// K2: part2 = relu(reduce16(part1)+b1a) @ W1b.  K=2048, BK=64; grid (2, 32)
__global__ __launch_bounds__(256) void gemm_l1b(const float* __restrict__ part1,
                                                const float* __restrict__ b1a,
                                                const float* __restrict__ W1b,
                                                float* __restrict__ part2) {
    __shared__ __align__(16) float sA[64 * 21];
    const int t = threadIdx.x, cb = blockIdx.x, kc = blockIdx.y;
    const int k0 = kc * 64;
    for (int idx = t; idx < NN * 64; idx += 256) {
        const int i = idx / 64, c = idx % 64;
        const int k = k0 + c;
        float s = b1a[k];
#pragma unroll
        for (int cc = 0; cc < 16; ++cc) s += part1[((size_t)cc * NN + i) * HID + k];
        sA[c * 21 + i] = s > 0.f ? s : 0.f;
    }
    __syncthreads();
    gemm_inner<64, HID>(cb * 1024 + 4 * t, kc, W1b, part2, sA);
}

// K3: part3 = (M @ relu(reduce32(part2)+b1b)) @ W2a.  K=2048, BK=64; grid (4,32)
__global__ __launch_bounds__(256) void gemm_l2a(const float* __restrict__ part2,
                                                const float* __restrict__ b1b,
                                                const int* __restrict__ ei,
                                                const float* __restrict__ W2a,
                                                float* __restrict__ part3) {
    __shared__ __align__(16) float sA[64 * 21];
    __shared__ __align__(16) float sZ[64 * 21];
    __shared__ float sM[NN * NN];
    __shared__ int scratch[NN * NN + 1];
    const int t = threadIdx.x, cb = blockIdx.x, kc = blockIdx.y;
    const int k0 = kc * 64;
    build_M(ei, sM, scratch, t, 256);
    for (int idx = t; idx < NN * 64; idx += 256) {
        const int i = idx / 64, c = idx % 64;
        const int k = k0 + c;
        float s = b1b[k];
#pragma unroll
        for (int cc = 0; cc < 32; ++cc) s += part2[((size_t)cc * NN + i) * HID + k];
        sZ[c * 21 + i] = s > 0.f ? s : 0.f;
    }
    __syncthreads();
    for (int idx = t; idx < NN * 64; idx += 256) {
        const int i = idx / 64, c = idx % 64;
        float acc = 0.f;
#pragma unroll
        for (int s = 0; s < NN; ++s) acc = fmaf(sM[i * NN + s], sZ[c * 21 + s], acc);
        sA[c * 21 + i] = acc;
    }
    __syncthreads();
    gemm_inner<64, NT>(cb * 1024 + 4 * t, kc, W2a, part3, sA);
}

// K4: part4 = relu(reduce32(part3)+b2a) @ W2b.  K=4096, BK=64; grid (4, 64)
__global__ __launch_bounds__(256) void gemm_l2b(const float* __restrict__ part3,
                                                const float* __restrict__ b2a,
                                                const float* __restrict__ W2b,
                                                float* __restrict__ part4) {
    __shared__ __align__(16) float sA[64 * 21];
    const int t = threadIdx.x, cb = blockIdx.x, kc = blockIdx.y;
    const int k0 = kc * 64;
    for (int idx = t; idx < NN * 64; idx += 256) {
        const int i = idx / 64, c = idx % 64;
        const int k = k0 + c;
        float s = b2a[k];
#pragma unroll
        for (int cc = 0; cc < 32; ++cc) s += part3[((size_t)cc * NN + i) * NT + k];
        sA[c * 21 + i] = s > 0.f ? s : 0.f;
    }
    __syncthreads();
    gemm_inner<64, NT>(cb * 1024 + 4 * t, kc, W2b, part4, sA);
}

// K5: flat = reduce64(part4)+b2b -> out+1.  76 blocks x 256 threads, float4.
__global__ __launch_bounds__(256) void reduce_out(const float* __restrict__ part4,
                                                  const float* __restrict__ b2b,
                                                  float* __restrict__ out1) {
    const int f = blockIdx.x * 256 + threadIdx.x;
    const int i = f / (NT / 4), n4 = f % (NT / 4);
    const float4 b = ((const float4*)b2b)[n4];
    float4 s = b;
    const float4* __restrict__ p = (const float4*)part4 + (size_t)i * (NT / 4) + n4;
#pragma unroll 16
    for (int c = 0; c < 64; ++c) {
        const float4 v = p[(size_t)c * NN * (NT / 4)];
        s.x += v.x; s.y += v.y; s.z += v.z; s.w += v.w;
    }
    float* __restrict__ o = out1 + ((size_t)i * (NT / 4) + n4) * 4;
    o[0] = s.x; o[1] = s.y; o[2] = s.z; o[3] = s.w;
}

// ---------------------------------------------------------------------------
// K6 (dense-front DMA classifier): 512 blocks x 256 threads.
//   Step s (38 steps): device reads ONE contiguous 4 MB slab of Wc1
//   (77824 rows x 2 KB = 512 blocks x 8 KB x 38 steps, exact). Block b's
//   8 KB (rows s*2048+b*4 .. +3) is DMA'd to LDS (4-buffer rotation, 3 slabs
//   ahead, counted vmcnt, RAW s_barrier so the compiler can't drain vmcnt).
//   flat values pre-staged to LDS so vmcnt counts ONLY DMA ops.
//   Thread t owns cols (2t,2t+1): acc += flat[row]*Wc1[row][col]; per-block
//   partial dotted with Wc2 -> scal[b]; ticket: last of 512 sums + sigmoid.
// ---------------------------------------------------------------------------
__global__ __launch_bounds__(256, 2) void cls_dma(const float* __restrict__ flat,
                                                  const float* __restrict__ Wc1,
                                                  const float* __restrict__ bc1,
                                                  const float* __restrict__ Wc2,
                                                  const float* __restrict__ bc2,
                                                  float* __restrict__ out,
                                                  float* __restrict__ scal,
                                                  unsigned int* __restrict__ counter) {
    __shared__ __align__(16) float sW[4][2048];  // 4 bufs x 8 KB
    __shared__ float sF[152];                    // this block's flat values
    __shared__ float red[256];
    __shared__ int lastFlag;
    const int t = threadIdx.x, lane = t & 63, w = t >> 6;
    const int b = blockIdx.x;  // 0..511

    // pre-stage flat: sF[s*4+j] = flat[s*2048 + b*4 + j]; drains cleanly here
    if (t < 152) sF[t] = flat[(t >> 2) * 2048 + b * 4 + (t & 3)];
    const float2 wc2 = ((const float2*)Wc2)[t];
    __syncthreads();  // sF ready; all pre-loop vmem retires before first wait

    // DMA issue for slab s: wave w stages its 2 KB (rows are contiguous 8 KB)
#define ISSUE(s)                                                              \
    do {                                                                      \
        const float* g_ = Wc1 + ((size_t)((s) * 2048 + b * 4)) * 512 +        \
                          w * 512 + lane * 4;                                 \
        float* l_ = &sW[(s) & 3][w * 512];                                    \
        stage16B(g_, l_);                                                     \
        stage16B(g_ + 256, l_ + 256);                                         \
    } while (0)

    ISSUE(0); ISSUE(1); ISSUE(2);   // 6 DMA ops outstanding per wave
    float accx = 0.f, accy = 0.f;
#pragma unroll 1
    for (int s = 0; s < 38; ++s) {
        __builtin_amdgcn_s_barrier();   // all waves done consuming slab s-1
        if (s + 3 < 38) ISSUE(s + 3);
        if (s <= 34)      asm volatile("s_waitcnt vmcnt(6)" ::: "memory");
        else if (s == 35) asm volatile("s_waitcnt vmcnt(4)" ::: "memory");
        else if (s == 36) asm volatile("s_waitcnt vmcnt(2)" ::: "memory");
        else              asm volatile("s_waitcnt vmcnt(0)" ::: "memory");
        __builtin_amdgcn_s_barrier();   // slab s complete for ALL waves
        const float* buf = sW[s & 3];
        const int fo = s * 4;
        const float f0 = sF[fo], f1 = sF[fo + 1], f2 = sF[fo + 2], f3 = sF[fo + 3];
        const float2 r0 = *(const float2*)(buf + 2 * t);
        const float2 r1 = *(const float2*)(buf + 512 + 2 * t);
        const float2 r2 = *(const float2*)(buf + 1024 + 2 * t);
        const float2 r3 = *(const float2*)(buf + 1536 + 2 * t);
        accx = fmaf(f0, r0.x, accx); accy = fmaf(f0, r0.y, accy);
        accx = fmaf(f1, r1.x, accx); accy = fmaf(f1, r1.y, accy);
        accx = fmaf(f2, r2.x, accx); accy = fmaf(f2, r2.y, accy);
        accx = fmaf(f3, r3.x, accx); accy = fmaf(f3, r3.y, accy);
    }
#undef ISSUE

    // block scalar = partial . Wc2
    __syncthreads();
    red[t] = accx * wc2.x + accy * wc2.y;
    __syncthreads();
    for (int off = 128; off > 0; off >>= 1) {
        if (t < off) red[t] += red[t + off];
        __syncthreads();
    }
    if (t == 0) scal[b] = red[0];
    __threadfence();  // release scal device-wide (cross-XCD)
    __syncthreads();
    if (t == 0) lastFlag = (atomicAdd(counter, 1u) == 511u) ? 1 : 0;
    __syncthreads();
    if (!lastFlag) return;
    __threadfence();  // acquire before reading all scal

    float s2 = scal[t] + scal[t + 256];
    const float2 b1 = ((const float2*)bc1)[t];
    s2 += b1.x * wc2.x + b1.y * wc2.y;
    red[t] = s2;
    __syncthreads();
    for (int off = 128; off > 0; off >>= 1) {
        if (t < off) red[t] += red[t + off];
        __syncthreads();
    }
    if (t == 0) out[0] = 1.f / (1.f + expf(-(red[0] + bc2[0])));
}

extern "C" void kernel_launch(void* const* d_in, const int* in_sizes, int n_in,
                              void* d_out, int out_size, void* d_ws, size_t ws_size,
                              hipStream_t stream) {
    const float* z   = (const float*)d_in[0];
    const int*   ei  = (const int*)d_in[1];
    const float* W1a = (const float*)d_in[2];
    const float* b1a = (const float*)d_in[3];
    const float* W1b = (const float*)d_in[4];
    const float* b1b = (const float*)d_in[5];
    const float* W2a = (const float*)d_in[6];
    const float* b2a = (const float*)d_in[7];
    const float* W2b = (const float*)d_in[8];
    const float* b2b = (const float*)d_in[9];
    const float* Wc1 = (const float*)d_in[10];
    const float* bc1 = (const float*)d_in[11];
    const float* Wc2 = (const float*)d_in[12];
    const float* bc2 = (const float*)d_in[13];
    float* out = (float*)d_out;
    float* ws  = (float*)d_ws;

    // workspace layout (float offsets)
    unsigned int* counter = (unsigned int*)ws;  // ticket, reset by K1 each call
    float* part1 = ws + 262144;    // 16*19*2048 =   622,592
    float* part2 = ws + 1048576;   // 32*19*2048 = 1,245,184
    float* part3 = ws + 2359296;   // 32*19*4096 = 2,490,368
    float* part4 = ws + 4980736;   // 64*19*4096 = 4,980,736
    float* scal  = ws + 10485760;  // 512

    gemm_l1a<<<dim3(2, 16), 256, 0, stream>>>(z, ei, W1a, part1, counter);
    gemm_l1b<<<dim3(2, 32), 256, 0, stream>>>(part1, b1a, W1b, part2);
    gemm_l2a<<<dim3(4, 32), 256, 0, stream>>>(part2, b1b, ei, W2a, part3);
    gemm_l2b<<<dim3(4, 64), 256, 0, stream>>>(part3, b2a, W2b, part4);
    reduce_out<<<76, 256, 0, stream>>>(part4, b2b, out + 1);
    cls_dma<<<512, 256, 0, stream>>>(out + 1, Wc1, bc1, Wc2, bc2,
                                     out, scal, counter);
}

// Round 15
// 163.496 us; speedup vs baseline: 1.6830x; 1.3707x over previous
//
#include <hip/hip_runtime.h>

#define NN 19        // nodes
#define NT 4096
#define LAT 512
#define HID 2048
#define NE 342       // edges

// ---------------------------------------------------------------------------
// Async global->LDS DMA, 16 B per lane (global_load_lds_dwordx4). r9-verified.
// ---------------------------------------------------------------------------
__device__ __forceinline__ void stage16B(const void* gsrc, void* ldst) {
    __builtin_amdgcn_global_load_lds(
        reinterpret_cast<const __attribute__((address_space(1))) void*>(
            reinterpret_cast<uintptr_t>(gsrc)),
        reinterpret_cast<__attribute__((address_space(3))) void*>(
            reinterpret_cast<uintptr_t>(ldst)),
        16, 0, 0);
}

// ---------------------------------------------------------------------------
// Build M = I + adjacency-count (19x19) into sM from edge_idx (i64/i32 auto).
// ---------------------------------------------------------------------------
__device__ __forceinline__ void build_M(const int* __restrict__ ei, float* sM,
                                        int* scratch, int t, int bs) {
    int* cnt = scratch;
    int* flag = scratch + NN * NN;
    if (t == 0) *flag = 0;
    for (int i = t; i < NN * NN; i += bs) cnt[i] = 0;
    __syncthreads();
    int f = 0;
    for (int i = t; i < NE; i += bs) f |= ei[2 * i + 1];
    if (f) atomicOr(flag, 1);
    __syncthreads();
    const bool i64 = (*flag == 0);
    for (int i = t; i < NE; i += bs) {
        const int s = i64 ? ei[2 * i] : ei[i];
        const int d = i64 ? ei[2 * NE + 2 * i] : ei[NE + i];
        atomicAdd(&cnt[d * NN + s], 1);
    }
    __syncthreads();
    for (int i = t; i < NN * NN; i += bs)
        sM[i] = (float)cnt[i] + ((i / NN) == (i % NN) ? 1.f : 0.f);
    __syncthreads();
}

// ---------------------------------------------------------------------------
// GEMM inner: acc[19][4 cols] over a BK k-slice staged in sA[k*21+i].
// ---------------------------------------------------------------------------
template <int BK, int N>
__device__ __forceinline__ void gemm_inner(int col, int kc,
                                           const float* __restrict__ W,
                                           float* __restrict__ part,
                                           const float* __restrict__ sA) {
    const int k0 = kc * BK;
    const float4* __restrict__ w = (const float4*)(W + (size_t)k0 * N + col);
    float4 acc[NN];
#pragma unroll
    for (int i = 0; i < NN; ++i) acc[i] = make_float4(0.f, 0.f, 0.f, 0.f);
#pragma unroll 1
    for (int kk = 0; kk < BK; kk += 8) {
        float4 wb[8];
#pragma unroll
        for (int u = 0; u < 8; ++u) wb[u] = w[(size_t)(kk + u) * (N / 4)];
#pragma unroll
        for (int u = 0; u < 8; ++u) {
#pragma unroll
            for (int i = 0; i < NN; ++i) {
                const float av = sA[(kk + u) * 21 + i];
                acc[i].x = fmaf(av, wb[u].x, acc[i].x);
                acc[i].y = fmaf(av, wb[u].y, acc[i].y);
                acc[i].z = fmaf(av, wb[u].z, acc[i].z);
                acc[i].w = fmaf(av, wb[u].w, acc[i].w);
            }
        }
    }
    float* __restrict__ p = part + (size_t)kc * NN * N + col;
#pragma unroll
    for (int i = 0; i < NN; ++i) *(float4*)(p + (size_t)i * N) = acc[i];
}

// K0: v[r] = Wc1[r,:] . Wc2  for r in [0, 77824).  1024 blocks x 4 waves.
// Wave gw handles rows r = s*4096 + gw, s = 0..18 (77824 = 19*4096): at any
// step the device sweeps ONE dense 8 MB window. Per-wave PRIVATE 3-deep LDS
// ring staged by DMA, counted vmcnt, NO barriers in the loop (waves fully
// decoupled). v buffered in LDS, bulk-stored at the end.
__global__ __launch_bounds__(256) void wc1_reduce(const float* __restrict__ Wc1,
                                                  const float* __restrict__ Wc2,
                                                  float* __restrict__ v) {
    __shared__ __align__(16) float sBuf[4][3][512];  // wave-private rings, 24 KB
    __shared__ float sV[4][19];
    const int t = threadIdx.x, lane = t & 63, w = t >> 6;
    const int gw = blockIdx.x * 4 + w;  // 0..4095

    // lane-private Wc2 quads (consumed every iter; compiler handles its wait)
    const float4 c0 = *(const float4*)(Wc2 + 4 * lane);
    const float4 c1 = *(const float4*)(Wc2 + 256 + 4 * lane);

#define ISS(s)                                                                \
    do {                                                                      \
        const float* g_ = Wc1 + ((size_t)(s) * 4096 + gw) * 512 + lane * 4;   \
        float* l_ = &sBuf[w][(s) % 3][0];                                     \
        stage16B(g_, l_);                                                     \
        stage16B(g_ + 256, l_ + 256);                                         \
    } while (0)

    ISS(0);
    ISS(1);
#pragma unroll 1
    for (int s = 0; s < 19; ++s) {
        if (s + 2 < 19) ISS(s + 2);
        if (s < 17)       asm volatile("s_waitcnt vmcnt(4)" ::: "memory");
        else if (s == 17) asm volatile("s_waitcnt vmcnt(2)" ::: "memory");
        else              asm volatile("s_waitcnt vmcnt(0)" ::: "memory");
        const float4 a = *(const float4*)&sBuf[w][s % 3][4 * lane];
        const float4 b = *(const float4*)&sBuf[w][s % 3][256 + 4 * lane];
        float d = a.x * c0.x + a.y * c0.y + a.z * c0.z + a.w * c0.w +
                  b.x * c1.x + b.y * c1.y + b.z * c1.z + b.w * c1.w;
#pragma unroll
        for (int off = 32; off > 0; off >>= 1) d += __shfl_xor(d, off, 64);
        if (lane == 0) sV[w][s] = d;
    }
#undef ISS
    __syncthreads();
    if (t < 76) {
        const int w_ = t / 19, s_ = t % 19;
        v[s_ * 4096 + blockIdx.x * 4 + w_] = sV[w_][s_];
    }
}

// K1: part1 = (M @ z) @ W1a.  K=512, BK=32; grid (cb=2, kc=16). Zeroes ticket.
__global__ __launch_bounds__(256) void gemm_l1a(const float* __restrict__ z,
                                                const int* __restrict__ ei,
                                                const float* __restrict__ W1a,
                                                float* __restrict__ part1,
                                                unsigned int* __restrict__ counter) {
    __shared__ __align__(16) float sA[32 * 21];
    __shared__ __align__(16) float sZ[32 * 21];
    __shared__ float sM[NN * NN];
    __shared__ int scratch[NN * NN + 1];
    const int t = threadIdx.x, cb = blockIdx.x, kc = blockIdx.y;
    const int k0 = kc * 32;
    if (cb == 0 && kc == 0 && t == 0) *counter = 0u;
    build_M(ei, sM, scratch, t, 256);
    for (int idx = t; idx < NN * 32; idx += 256) {
        const int s = idx / 32, c = idx % 32;
        sZ[c * 21 + s] = z[(size_t)s * LAT + k0 + c];
    }
    __syncthreads();
    for (int idx = t; idx < NN * 32; idx += 256) {
        const int i = idx / 32, c = idx % 32;
        float acc = 0.f;
#pragma unroll
        for (int s = 0; s < NN; ++s) acc = fmaf(sM[i * NN + s], sZ[c * 21 + s], acc);
        sA[c * 21 + i] = acc;
    }
    __syncthreads();
    gemm_inner<32, HID>(cb * 1024 + 4 * t, kc, W1a, part1, sA);
}

// K2: part2 = relu(reduce16(part1)+b1a) @ W1b.  K=2048, BK=64; grid (2, 32)
__global__ __launch_bounds__(256) void gemm_l1b(const float* __restrict__ part1,
                                                const float* __restrict__ b1a,
                                                const float* __restrict__ W1b,
                                                float* __restrict__ part2) {
    __shared__ __align__(16) float sA[64 * 21];
    const int t = threadIdx.x, cb = blockIdx.x, kc = blockIdx.y;
    const int k0 = kc * 64;
    for (int idx = t; idx < NN * 64; idx += 256) {
        const int i = idx / 64, c = idx % 64;
        const int k = k0 + c;
        float s = b1a[k];
#pragma unroll
        for (int cc = 0; cc < 16; ++cc) s += part1[((size_t)cc * NN + i) * HID + k];
        sA[c * 21 + i] = s > 0.f ? s : 0.f;
    }
    __syncthreads();
    gemm_inner<64, HID>(cb * 1024 + 4 * t, kc, W1b, part2, sA);
}

// K3: part3 = (M @ relu(reduce32(part2)+b1b)) @ W2a.  K=2048, BK=64; grid (4,32)
__global__ __launch_bounds__(256) void gemm_l2a(const float* __restrict__ part2,
                                                const float* __restrict__ b1b,
                                                const int* __restrict__ ei,
                                                const float* __restrict__ W2a,
                                                float* __restrict__ part3) {
    __shared__ __align__(16) float sA[64 * 21];
    __shared__ __align__(16) float sZ[64 * 21];
    __shared__ float sM[NN * NN];
    __shared__ int scratch[NN * NN + 1];
    const int t = threadIdx.x, cb = blockIdx.x, kc = blockIdx.y;
    const int k0 = kc * 64;
    build_M(ei, sM, scratch, t, 256);
    for (int idx = t; idx < NN * 64; idx += 256) {
        const int i = idx / 64, c = idx % 64;
        const int k = k0 + c;
        float s = b1b[k];
#pragma unroll
        for (int cc = 0; cc < 32; ++cc) s += part2[((size_t)cc * NN + i) * HID + k];
        sZ[c * 21 + i] = s > 0.f ? s : 0.f;
    }
    __syncthreads();
    for (int idx = t; idx < NN * 64; idx += 256) {
        const int i = idx / 64, c = idx % 64;
        float acc = 0.f;
#pragma unroll
        for (int s = 0; s < NN; ++s) acc = fmaf(sM[i * NN + s], sZ[c * 21 + s], acc);
        sA[c * 21 + i] = acc;
    }
    __syncthreads();
    gemm_inner<64, NT>(cb * 1024 + 4 * t, kc, W2a, part3, sA);
}

// K4: part4 = relu(reduce32(part3)+b2a) @ W2b.  K=4096, BK=64; grid (4, 64)
__global__ __launch_bounds__(256) void gemm_l2b(const float* __restrict__ part3,
                                                const float* __restrict__ b2a,
                                                const float* __restrict__ W2b,
                                                float* __restrict__ part4) {
    __shared__ __align__(16) float sA[64 * 21];
    const int t = threadIdx.x, cb = blockIdx.x, kc = blockIdx.y;
    const int k0 = kc * 64;
    for (int idx = t; idx < NN * 64; idx += 256) {
        const int i = idx / 64, c = idx % 64;
        const int k = k0 + c;
        float s = b2a[k];
#pragma unroll
        for (int cc = 0; cc < 32; ++cc) s += part3[((size_t)cc * NN + i) * NT + k];
        sA[c * 21 + i] = s > 0.f ? s : 0.f;
    }
    __syncthreads();
    gemm_inner<64, NT>(cb * 1024 + 4 * t, kc, W2b, part4, sA);
}

// K5: flat = reduce64(part4)+b2b -> out+1  AND  dem = sigmoid(flat.v + c).
// 76 blocks x 256 threads (float4 per thread); per-block partial of flat.v;
// device-scope ticket: last of 76 blocks adds bc1.Wc2 + bc2, applies sigmoid.
__global__ __launch_bounds__(256) void reduce_fin(const float* __restrict__ part4,
                                                  const float* __restrict__ b2b,
                                                  const float* __restrict__ v,
                                                  const float* __restrict__ bc1,
                                                  const float* __restrict__ Wc2,
                                                  const float* __restrict__ bc2,
                                                  float* __restrict__ out,
                                                  float* __restrict__ scal,
                                                  unsigned int* __restrict__ counter) {
    __shared__ float red[256];
    __shared__ int lastFlag;
    const int t = threadIdx.x;
    const int idx = blockIdx.x * 256 + t;        // 0..19455 quads
    const int i = idx / (NT / 4), n4 = idx % (NT / 4);
    const float4 b = ((const float4*)b2b)[n4];
    float4 s = b;
    const float4* __restrict__ p = (const float4*)part4 + (size_t)i * (NT / 4) + n4;
#pragma unroll 16
    for (int c = 0; c < 64; ++c) {
        const float4 q = p[(size_t)c * NN * (NT / 4)];
        s.x += q.x; s.y += q.y; s.z += q.z; s.w += q.w;
    }
    float* __restrict__ o = out + 1 + (size_t)idx * 4;
    o[0] = s.x; o[1] = s.y; o[2] = s.z; o[3] = s.w;

    // partial of flat . v
    const float4 vq = ((const float4*)v)[idx];
    red[t] = s.x * vq.x + s.y * vq.y + s.z * vq.z + s.w * vq.w;
    __syncthreads();
    for (int off = 128; off > 0; off >>= 1) {
        if (t < off) red[t] += red[t + off];
        __syncthreads();
    }
    if (t == 0) scal[blockIdx.x] = red[0];
    __threadfence();
    __syncthreads();
    if (t == 0) lastFlag = (atomicAdd(counter, 1u) == 75u) ? 1 : 0;
    __syncthreads();
    if (!lastFlag) return;
    __threadfence();

    float s2 = (t < 76) ? scal[t] : 0.f;
    const float2 b1 = ((const float2*)bc1)[t];
    const float2 w2 = ((const float2*)Wc2)[t];
    s2 += b1.x * w2.x + b1.y * w2.y;             // bc1 . Wc2 distributed
    red[t] = s2;
    __syncthreads();
    for (int off = 128; off > 0; off >>= 1) {
        if (t < off) red[t] += red[t + off];
        __syncthreads();
    }
    if (t == 0) out[0] = 1.f / (1.f + expf(-(red[0] + bc2[0])));
}

extern "C" void kernel_launch(void* const* d_in, const int* in_sizes, int n_in,
                              void* d_out, int out_size, void* d_ws, size_t ws_size,
                              hipStream_t stream) {
    const float* z   = (const float*)d_in[0];
    const int*   ei  = (const int*)d_in[1];
    const float* W1a = (const float*)d_in[2];
    const float* b1a = (const float*)d_in[3];
    const float* W1b = (const float*)d_in[4];
    const float* b1b = (const float*)d_in[5];
    const float* W2a = (const float*)d_in[6];
    const float* b2a = (const float*)d_in[7];
    const float* W2b = (const float*)d_in[8];
    const float* b2b = (const float*)d_in[9];
    const float* Wc1 = (const float*)d_in[10];
    const float* bc1 = (const float*)d_in[11];
    const float* Wc2 = (const float*)d_in[12];
    const float* bc2 = (const float*)d_in[13];
    float* out = (float*)d_out;
    float* ws  = (float*)d_ws;

    // workspace layout (float offsets)
    unsigned int* counter = (unsigned int*)ws;  // ticket, reset by K1 each call
    float* vvec  = ws + 131072;    // 77824
    float* part1 = ws + 262144;    // 16*19*2048 =   622,592
    float* part2 = ws + 1048576;   // 32*19*2048 = 1,245,184
    float* part3 = ws + 2359296;   // 32*19*4096 = 2,490,368
    float* part4 = ws + 4980736;   // 64*19*4096 = 4,980,736
    float* scal  = ws + 10485760;  // 76

    wc1_reduce<<<1024, 256, 0, stream>>>(Wc1, Wc2, vvec);
    gemm_l1a<<<dim3(2, 16), 256, 0, stream>>>(z, ei, W1a, part1, counter);
    gemm_l1b<<<dim3(2, 32), 256, 0, stream>>>(part1, b1a, W1b, part2);
    gemm_l2a<<<dim3(4, 32), 256, 0, stream>>>(part2, b1b, ei, W2a, part3);
    gemm_l2b<<<dim3(4, 64), 256, 0, stream>>>(part3, b2a, W2b, part4);
    reduce_fin<<<76, 256, 0, stream>>>(part4, b2b, vvec, bc1, Wc2, bc2,
                                       out, scal, counter);
}